// Round 4
// baseline (8081.351 us; speedup 1.0000x reference)
//
#include <hip/hip_runtime.h>
#include <hip/hip_fp16.h>

#define CC 256
#define NN 4096
#define NB 8
#define NM ((size_t)CC * NN)   // 1M elems per [C][N] plane

// ---------------------------------------------------------------------------
// proj: plane[o,n] = fp16( sum_c W[o,c] * x[c,n] * m(n) + bias[o] )
// grid (NN/64, CC/64, nb), block 256. invmask: 0 -> m, 1 -> 1-m
// slot layout (halfs): [q | k | v | o], each NM.
// ---------------------------------------------------------------------------
__global__ __launch_bounds__(256) void proj_kernel(
    const float* __restrict__ x, const float* __restrict__ mask,
    const float* __restrict__ W, const float* __restrict__ bias,
    __half* __restrict__ wsh, int invmask, int qkv_off, int b0)
{
    const int slot = blockIdx.z;
    const int b = b0 + slot;
    const float* xb = x + (size_t)b * NM;
    const float* mb = mask + (size_t)b * NN;
    __half* out = wsh + ((size_t)slot * 4 + qkv_off) * NM;

    __shared__ float sW[16][65];   // [c][o]
    __shared__ float sX[16][65];   // [c][n]
    const int t  = threadIdx.x;
    const int n0 = blockIdx.x * 64;
    const int o0 = blockIdx.y * 64;
    const int tx = t & 15, ty = t >> 4;
    const int ln = t & 63, lc = t >> 6;
    const int wj = t & 15, wi = t >> 4;

    float mm   = mb[n0 + ln];
    float mval = invmask ? (1.0f - mm) : mm;

    float acc[4][4] = {};
    for (int c0 = 0; c0 < CC; c0 += 16) {
#pragma unroll
        for (int r = 0; r < 4; ++r) {
            int i = wi + 16 * r;
            sW[wj][i] = W[(o0 + i) * CC + c0 + wj];
        }
#pragma unroll
        for (int r = 0; r < 4; ++r) {
            int cc2 = lc * 4 + r;
            sX[cc2][ln] = xb[(size_t)(c0 + cc2) * NN + n0 + ln] * mval;
        }
        __syncthreads();
#pragma unroll
        for (int kk = 0; kk < 16; ++kk) {
            float a[4], bb[4];
#pragma unroll
            for (int i = 0; i < 4; ++i) a[i] = sW[kk][ty * 4 + i];
#pragma unroll
            for (int j = 0; j < 4; ++j) bb[j] = sX[kk][tx * 4 + j];
#pragma unroll
            for (int i = 0; i < 4; ++i)
#pragma unroll
                for (int j = 0; j < 4; ++j)
                    acc[i][j] = fmaf(a[i], bb[j], acc[i][j]);
        }
        __syncthreads();
    }
#pragma unroll
    for (int i = 0; i < 4; ++i) {
        int o = o0 + ty * 4 + i;
        float bv = bias[o];
#pragma unroll
        for (int j = 0; j < 4; ++j)
            out[(size_t)o * NN + n0 + tx * 4 + j] = __float2half(acc[i][j] + bv);
    }
}

// ---------------------------------------------------------------------------
// flash attention: per block = one 64-query tile of one batch-slot.
// o[c,n] = sum_m softmax_m(q.k)[n,m] * v[c,m], online softmax, fp32 internal.
// grid (NN/64, nb), block 256.
// ---------------------------------------------------------------------------
__global__ __launch_bounds__(256) void flash_kernel(__half* __restrict__ wsh)
{
    __shared__ float sQ[16][68];
    __shared__ float sK[16][68];
    __shared__ float sP[64][68];   // [n][m] probabilities tile
    __shared__ float sV[64][68];   // [c_local][m] value tile
    __shared__ float Mrow[64], Lrow[64], Arow[64];

    const int t  = threadIdx.x;
    const int n0 = blockIdx.x * 64;
    __half* base = wsh + (size_t)blockIdx.y * 4 * NM;
    const __half* q = base;
    const __half* k = base + NM;
    const __half* v = base + 2 * NM;
    __half* o = base + 3 * NM;

    const int ry  = t >> 4;    // S phase: rows n = ry*4..+3
    const int cx  = t & 15;    // S phase: cols m = cx*4..+3
    const int ty2 = t >> 4;    // PV phase: channel = cc*16 + ty2
    const int tx2 = t & 15;    // PV phase: n = tx2*4..+3
    const int lc  = t >> 6, ln = t & 63;   // loaders

    if (t < 64) { Mrow[t] = -3.0e38f; Lrow[t] = 0.f; }
    float o_acc[16][4];
#pragma unroll
    for (int a = 0; a < 16; ++a)
#pragma unroll
        for (int b = 0; b < 4; ++b) o_acc[a][b] = 0.f;
    __syncthreads();

    for (int mt = 0; mt < NN / 64; ++mt) {
        const int m0 = mt * 64;
        // ---- S = q^T k for this 64x64 tile (K-dim = 256 channels) ----
        float s_acc[4][4] = {};
        for (int c0 = 0; c0 < CC; c0 += 16) {
            __syncthreads();
#pragma unroll
            for (int r = 0; r < 4; ++r) {
                int cc2 = lc * 4 + r;
                sQ[cc2][ln] = __half2float(q[(size_t)(c0 + cc2) * NN + n0 + ln]);
                sK[cc2][ln] = __half2float(k[(size_t)(c0 + cc2) * NN + m0 + ln]);
            }
            __syncthreads();
#pragma unroll
            for (int kk = 0; kk < 16; ++kk) {
                float4 a4 = *(const float4*)&sQ[kk][ry * 4];
                float4 b4 = *(const float4*)&sK[kk][cx * 4];
                float av[4] = {a4.x, a4.y, a4.z, a4.w};
                float bv[4] = {b4.x, b4.y, b4.z, b4.w};
#pragma unroll
                for (int i = 0; i < 4; ++i)
#pragma unroll
                    for (int j = 0; j < 4; ++j)
                        s_acc[i][j] = fmaf(av[i], bv[j], s_acc[i][j]);
            }
        }
        // ---- online softmax over this tile ----
#pragma unroll
        for (int i = 0; i < 4; ++i) {
            int r = ry * 4 + i;
            float tm = fmaxf(fmaxf(s_acc[i][0], s_acc[i][1]),
                             fmaxf(s_acc[i][2], s_acc[i][3]));
#pragma unroll
            for (int mm = 1; mm < 16; mm <<= 1) tm = fmaxf(tm, __shfl_xor(tm, mm, 64));
            float Mold = Mrow[r];
            float Mnew = fmaxf(Mold, tm);
            float rs = 0.f;
#pragma unroll
            for (int j = 0; j < 4; ++j) {
                float p = __expf(s_acc[i][j] - Mnew);
                s_acc[i][j] = p;
                rs += p;
            }
#pragma unroll
            for (int mm = 1; mm < 16; mm <<= 1) rs += __shfl_xor(rs, mm, 64);
            if (cx == 0) {           // one owner lane per row; same wave as readers
                float alpha = __expf(Mold - Mnew);
                Arow[r] = alpha;
                Mrow[r] = Mnew;
                Lrow[r] = Lrow[r] * alpha + rs;
            }
            *(float4*)&sP[r][cx * 4] =
                make_float4(s_acc[i][0], s_acc[i][1], s_acc[i][2], s_acc[i][3]);
        }
        __syncthreads();   // sP, Arow visible to PV mapping
        // ---- PV: o_acc = o_acc*alpha + P * V^T  ----
        float a_j[4];
#pragma unroll
        for (int j = 0; j < 4; ++j) a_j[j] = Arow[tx2 * 4 + j];
#pragma unroll
        for (int cc = 0; cc < 16; ++cc)
#pragma unroll
            for (int j = 0; j < 4; ++j) o_acc[cc][j] *= a_j[j];

        for (int ci = 0; ci < 4; ++ci) {      // 4 chunks of 64 channels
            __syncthreads();
#pragma unroll
            for (int r = 0; r < 16; ++r) {
                int cl = lc * 16 + r;
                sV[cl][ln] = __half2float(v[(size_t)(ci * 64 + cl) * NN + m0 + ln]);
            }
            __syncthreads();
#pragma unroll
            for (int mq = 0; mq < 16; ++mq) {
                float4 p4[4];
#pragma unroll
                for (int j = 0; j < 4; ++j)
                    p4[j] = *(const float4*)&sP[tx2 * 4 + j][mq * 4];
#pragma unroll
                for (int cc_l = 0; cc_l < 4; ++cc_l) {
                    int cc = ci * 4 + cc_l;
                    int cl = cc_l * 16 + ty2;
                    float4 v4 = *(const float4*)&sV[cl][mq * 4];
#pragma unroll
                    for (int j = 0; j < 4; ++j) {
                        o_acc[cc][j] = fmaf(p4[j].x, v4.x, o_acc[cc][j]);
                        o_acc[cc][j] = fmaf(p4[j].y, v4.y, o_acc[cc][j]);
                        o_acc[cc][j] = fmaf(p4[j].z, v4.z, o_acc[cc][j]);
                        o_acc[cc][j] = fmaf(p4[j].w, v4.w, o_acc[cc][j]);
                    }
                }
            }
        }
        __syncthreads();   // all sP reads done before next tile rewrites it
    }
    // ---- finalize: divide by denominator, write o (fp16) ----
    float inv[4];
#pragma unroll
    for (int j = 0; j < 4; ++j) inv[j] = 1.0f / Lrow[tx2 * 4 + j];
#pragma unroll
    for (int cc = 0; cc < 16; ++cc) {
        int c = cc * 16 + ty2;
#pragma unroll
        for (int j = 0; j < 4; ++j)
            o[(size_t)c * NN + n0 + tx2 * 4 + j] =
                __float2half(o_acc[cc][j] * inv[j]);
    }
}

// ---------------------------------------------------------------------------
// final: out[o,n] = sum_c Wo[o,c]*O[c,n] + bo[o] + gamma*x[o,n]   (fp32 out)
// grid (NN/64, CC/64, nb), block 256
// ---------------------------------------------------------------------------
__global__ __launch_bounds__(256) void final_kernel(
    const __half* __restrict__ wsh, const float* __restrict__ Wo,
    const float* __restrict__ bo, const float* __restrict__ x,
    const float* __restrict__ gamma, float* __restrict__ outall, int b0)
{
    const int slot = blockIdx.z;
    const int b = b0 + slot;
    const __half* O = wsh + ((size_t)slot * 4 + 3) * NM;
    const float* xb = x + (size_t)b * NM;
    float* out = outall + (size_t)b * NM;

    __shared__ float sW[16][65];
    __shared__ float sX[16][65];
    const int t  = threadIdx.x;
    const int n0 = blockIdx.x * 64;
    const int o0 = blockIdx.y * 64;
    const int tx = t & 15, ty = t >> 4;
    const int ln = t & 63, lc = t >> 6;
    const int wj = t & 15, wi = t >> 4;

    float acc[4][4] = {};
    for (int c0 = 0; c0 < CC; c0 += 16) {
#pragma unroll
        for (int r = 0; r < 4; ++r) {
            int i = wi + 16 * r;
            sW[wj][i] = Wo[(o0 + i) * CC + c0 + wj];
        }
#pragma unroll
        for (int r = 0; r < 4; ++r) {
            int cc2 = lc * 4 + r;
            sX[cc2][ln] = __half2float(O[(size_t)(c0 + cc2) * NN + n0 + ln]);
        }
        __syncthreads();
#pragma unroll
        for (int kk = 0; kk < 16; ++kk) {
            float a[4], bb[4];
#pragma unroll
            for (int i = 0; i < 4; ++i) a[i] = sW[kk][ty * 4 + i];
#pragma unroll
            for (int j = 0; j < 4; ++j) bb[j] = sX[kk][tx * 4 + j];
#pragma unroll
            for (int i = 0; i < 4; ++i)
#pragma unroll
                for (int j = 0; j < 4; ++j)
                    acc[i][j] = fmaf(a[i], bb[j], acc[i][j]);
        }
        __syncthreads();
    }
    float g = gamma[0];
#pragma unroll
    for (int i = 0; i < 4; ++i) {
        int o = o0 + ty * 4 + i;
        float bv = bo[o];
#pragma unroll
        for (int j = 0; j < 4; ++j) {
            int n = n0 + tx * 4 + j;
            out[(size_t)o * NN + n] = acc[i][j] + bv + g * xb[(size_t)o * NN + n];
        }
    }
}

// ---------------------------------------------------------------------------
// fallback signal: ws too small -> write all 1.0f
// ---------------------------------------------------------------------------
__global__ __launch_bounds__(256) void ones_kernel(float* __restrict__ out, int total)
{
    for (int i = blockIdx.x * 256 + threadIdx.x; i < total; i += gridDim.x * 256)
        out[i] = 1.0f;
}

// ---------------------------------------------------------------------------
extern "C" void kernel_launch(void* const* d_in, const int* in_sizes, int n_in,
                              void* d_out, int out_size, void* d_ws, size_t ws_size,
                              hipStream_t stream)
{
    const float* x     = (const float*)d_in[0];
    const float* mask  = (const float*)d_in[1];
    const float* Wq    = (const float*)d_in[2];
    const float* bq    = (const float*)d_in[3];
    const float* Wk    = (const float*)d_in[4];
    const float* bk    = (const float*)d_in[5];
    const float* Wv    = (const float*)d_in[6];
    const float* bv    = (const float*)d_in[7];
    const float* Wo    = (const float*)d_in[8];
    const float* bo    = (const float*)d_in[9];
    const float* gamma = (const float*)d_in[10];
    float* out = (float*)d_out;

    // ws: nb slots of [q|k|v|o] fp16 planes, 8 MiB each
    const size_t slot_bytes = 4 * NM * sizeof(__half);
    __half* wsh = (__half*)d_ws;
    int nb = (int)(ws_size / slot_bytes);
    if (nb < 1) {
        ones_kernel<<<2048, 256, 0, stream>>>(out, out_size);
        return;
    }
    if (nb > NB) nb = NB;

    for (int b0 = 0; b0 < NB; b0 += nb) {
        int nbc = NB - b0; if (nbc > nb) nbc = nb;
        dim3 gP(NN / 64, CC / 64, nbc);
        dim3 gF(NN / 64, nbc);
        proj_kernel<<<gP, 256, 0, stream>>>(x, mask, Wq, bq, wsh, 0, 0, b0);
        proj_kernel<<<gP, 256, 0, stream>>>(x, mask, Wk, bk, wsh, 1, 1, b0);
        proj_kernel<<<gP, 256, 0, stream>>>(x, mask, Wv, bv, wsh, 1, 2, b0);
        flash_kernel<<<gF, 256, 0, stream>>>(wsh);
        final_kernel<<<gP, 256, 0, stream>>>(wsh, Wo, bo, x, gamma, out, b0);
    }
}

// Round 5
// 1329.741 us; speedup vs baseline: 6.0774x; 6.0774x over previous
//
#include <hip/hip_runtime.h>

#define CC 256
#define NN 4096
#define NB 8
#define NM ((size_t)CC * NN)   // 1M elems per plane

typedef _Float16 f16;
typedef f16 f16x4 __attribute__((ext_vector_type(4)));
typedef f16 f16x8 __attribute__((ext_vector_type(8)));
typedef float f32x4 __attribute__((ext_vector_type(4)));

// ---------------------------------------------------------------------------
// proj: Y[o,n] = sum_c W[o,c] * x[c,n] * m(n) + bias[o]  -> fp16 plane
// transout=0: plane[o][n] (c-major, for V). transout=1: plane[n][o] (for Q,K).
// grid (NN/64, CC/64, nb), block 256.
// ---------------------------------------------------------------------------
__global__ __launch_bounds__(256) void proj_kernel(
    const float* __restrict__ x, const float* __restrict__ mask,
    const float* __restrict__ W, const float* __restrict__ bias,
    f16* __restrict__ wsh, int invmask, int qkv_off, int b0, int transout)
{
    const int slot = blockIdx.z;
    const int b = b0 + slot;
    const float* xb = x + (size_t)b * NM;
    const float* mb = mask + (size_t)b * NN;
    f16* out = wsh + ((size_t)slot * 4 + qkv_off) * NM;

    __shared__ float sW[16][65];   // [c][o]
    __shared__ float sX[16][65];   // [c][n]
    const int t  = threadIdx.x;
    const int n0 = blockIdx.x * 64;
    const int o0 = blockIdx.y * 64;
    const int tx = t & 15, ty = t >> 4;
    const int ln = t & 63, lc = t >> 6;
    const int wj = t & 15, wi = t >> 4;

    float mm   = mb[n0 + ln];
    float mval = invmask ? (1.0f - mm) : mm;

    float acc[4][4] = {};
    for (int c0 = 0; c0 < CC; c0 += 16) {
#pragma unroll
        for (int r = 0; r < 4; ++r) {
            int i = wi + 16 * r;
            sW[wj][i] = W[(o0 + i) * CC + c0 + wj];
        }
#pragma unroll
        for (int r = 0; r < 4; ++r) {
            int cc2 = lc * 4 + r;
            sX[cc2][ln] = xb[(size_t)(c0 + cc2) * NN + n0 + ln] * mval;
        }
        __syncthreads();
#pragma unroll
        for (int kk = 0; kk < 16; ++kk) {
            float a[4], bb[4];
#pragma unroll
            for (int i = 0; i < 4; ++i) a[i] = sW[kk][ty * 4 + i];
#pragma unroll
            for (int j = 0; j < 4; ++j) bb[j] = sX[kk][tx * 4 + j];
#pragma unroll
            for (int i = 0; i < 4; ++i)
#pragma unroll
                for (int j = 0; j < 4; ++j)
                    acc[i][j] = fmaf(a[i], bb[j], acc[i][j]);
        }
        __syncthreads();
    }
    float bvv[4];
#pragma unroll
    for (int i = 0; i < 4; ++i) bvv[i] = bias[o0 + ty * 4 + i];

    if (transout) {
        // out[n][o]: pack over i (o-dim), one 8B store per j
#pragma unroll
        for (int j = 0; j < 4; ++j) {
            f16x4 pk;
#pragma unroll
            for (int i = 0; i < 4; ++i) pk[i] = (f16)(acc[i][j] + bvv[i]);
            *(f16x4*)(out + (size_t)(n0 + tx * 4 + j) * CC + o0 + ty * 4) = pk;
        }
    } else {
        // out[o][n]: pack over j (n-dim), one 8B store per i
#pragma unroll
        for (int i = 0; i < 4; ++i) {
            f16x4 pk;
#pragma unroll
            for (int j = 0; j < 4; ++j) pk[j] = (f16)(acc[i][j] + bvv[i]);
            *(f16x4*)(out + (size_t)(o0 + ty * 4 + i) * NN + n0 + tx * 4) = pk;
        }
    }
}

// ---------------------------------------------------------------------------
// MFMA flash attention. grid (NN/64, nb), block 256 (4 waves).
// Wave w owns query rows [n0+w*16, n0+w*16+16). Q frags resident in regs.
// Layouts: q[N][C], k[M][C], v[C][N], o[C][N], all fp16.
// mfma_f32_16x16x32_f16: A[m=lane&15][k=quad*8+j], B[k=quad*8+j][n=lane&15],
// D col=lane&15, row=quad*4+reg.
// ---------------------------------------------------------------------------
__global__ __launch_bounds__(256) void flash_kernel(f16* __restrict__ wsh)
{
    __shared__ f16 pbuf[4][16 * 88];   // per-wave P tile, pitch 88 (16B-aligned rows)

    const int t    = threadIdx.x;
    const int w    = t >> 6;
    const int lane = t & 63;
    const int l16  = lane & 15;
    const int quad = lane >> 4;
    const int n0   = blockIdx.x * 64;

    f16* base = wsh + (size_t)blockIdx.y * 4 * NM;
    const f16* qt = base;            // [N][C]
    const f16* kt = base + NM;       // [M][C]
    const f16* vp = base + 2 * NM;   // [C][N]
    f16* op       = base + 3 * NM;   // [C][N]

    // Q fragments for the wave's 16 rows, all 256 channels (8 k-chunks)
    const int nrow = n0 + w * 16 + l16;
    f16x8 qf[8];
#pragma unroll
    for (int kc = 0; kc < 8; ++kc)
        qf[kc] = *(const f16x8*)(qt + (size_t)nrow * CC + kc * 32 + quad * 8);

    f32x4 oacc[16];
#pragma unroll
    for (int i = 0; i < 16; ++i) oacc[i] = (f32x4){0.f, 0.f, 0.f, 0.f};
    float M[4] = {-3.0e38f, -3.0e38f, -3.0e38f, -3.0e38f};
    float L[4] = {0.f, 0.f, 0.f, 0.f};

    f16* pw = &pbuf[w][0];

    for (int m0 = 0; m0 < NN; m0 += 64) {
        // ---- S = Q K^T : 16n x 64m, K-dim 256 ----
        f32x4 s[4];
#pragma unroll
        for (int ms = 0; ms < 4; ++ms) {
            f32x4 acc = {0.f, 0.f, 0.f, 0.f};
            const f16* kbase = kt + (size_t)(m0 + ms * 16 + l16) * CC + quad * 8;
#pragma unroll
            for (int kc = 0; kc < 8; ++kc) {
                f16x8 kf = *(const f16x8*)(kbase + kc * 32);
                acc = __builtin_amdgcn_mfma_f32_16x16x32_f16(qf[kc], kf, acc, 0, 0, 0);
            }
            s[ms] = acc;
        }
        // ---- online softmax (rows quad*4+r, private to 16-lane group) ----
        float Mnew[4], alpha[4];
#pragma unroll
        for (int r = 0; r < 4; ++r) {
            float tm = fmaxf(fmaxf(s[0][r], s[1][r]), fmaxf(s[2][r], s[3][r]));
            tm = fmaxf(tm, __shfl_xor(tm, 1, 64));
            tm = fmaxf(tm, __shfl_xor(tm, 2, 64));
            tm = fmaxf(tm, __shfl_xor(tm, 4, 64));
            tm = fmaxf(tm, __shfl_xor(tm, 8, 64));
            Mnew[r]  = fmaxf(M[r], tm);
            alpha[r] = __expf(M[r] - Mnew[r]);
            float p0 = __expf(s[0][r] - Mnew[r]);
            float p1 = __expf(s[1][r] - Mnew[r]);
            float p2 = __expf(s[2][r] - Mnew[r]);
            float p3 = __expf(s[3][r] - Mnew[r]);
            s[0][r] = p0; s[1][r] = p1; s[2][r] = p2; s[3][r] = p3;
            float rs = (p0 + p1) + (p2 + p3);
            rs += __shfl_xor(rs, 1, 64);
            rs += __shfl_xor(rs, 2, 64);
            rs += __shfl_xor(rs, 4, 64);
            rs += __shfl_xor(rs, 8, 64);
            L[r] = L[r] * alpha[r] + rs;
            M[r] = Mnew[r];
        }
        // ---- P -> LDS (fp16), D-layout write ----
#pragma unroll
        for (int ms = 0; ms < 4; ++ms)
#pragma unroll
            for (int r = 0; r < 4; ++r)
                pw[(quad * 4 + r) * 88 + ms * 16 + l16] = (f16)s[ms][r];
        // ---- rescale O only if the running max moved ----
        bool need = (alpha[0] < 1.f) | (alpha[1] < 1.f) |
                    (alpha[2] < 1.f) | (alpha[3] < 1.f);
        if (need) {
#pragma unroll
            for (int cs = 0; cs < 16; ++cs)
#pragma unroll
                for (int r = 0; r < 4; ++r) oacc[cs][r] *= alpha[r];
        }
        asm volatile("s_waitcnt lgkmcnt(0)" ::: "memory");
        // ---- P as A-fragments ----
        f16x8 pf[2];
#pragma unroll
        for (int kp = 0; kp < 2; ++kp)
            pf[kp] = *(const f16x8*)(pw + l16 * 88 + kp * 32 + quad * 8);
        // ---- O += P V^T : 16n x 256c ----
#pragma unroll
        for (int cs = 0; cs < 16; ++cs) {
            const f16* vbase = vp + (size_t)(cs * 16 + l16) * NN + m0 + quad * 8;
            f16x8 vf0 = *(const f16x8*)(vbase);
            f16x8 vf1 = *(const f16x8*)(vbase + 32);
            oacc[cs] = __builtin_amdgcn_mfma_f32_16x16x32_f16(pf[0], vf0, oacc[cs], 0, 0, 0);
            oacc[cs] = __builtin_amdgcn_mfma_f32_16x16x32_f16(pf[1], vf1, oacc[cs], 0, 0, 0);
        }
    }
    // ---- epilogue: divide by denominator, write o[C][N] fp16 ----
    float inv[4];
#pragma unroll
    for (int r = 0; r < 4; ++r) inv[r] = 1.0f / L[r];
#pragma unroll
    for (int cs = 0; cs < 16; ++cs)
#pragma unroll
        for (int r = 0; r < 4; ++r)
            op[(size_t)(cs * 16 + l16) * NN + n0 + w * 16 + quad * 4 + r] =
                (f16)(oacc[cs][r] * inv[r]);
}

// ---------------------------------------------------------------------------
// final: out[o,n] = sum_c Wo[o,c]*O[c,n] + bo[o] + gamma*x[o,n]   (fp32 out)
// grid (NN/64, CC/64, nb), block 256
// ---------------------------------------------------------------------------
__global__ __launch_bounds__(256) void final_kernel(
    const f16* __restrict__ wsh, const float* __restrict__ Wo,
    const float* __restrict__ bo, const float* __restrict__ x,
    const float* __restrict__ gamma, float* __restrict__ outall, int b0)
{
    const int slot = blockIdx.z;
    const int b = b0 + slot;
    const f16* O = wsh + ((size_t)slot * 4 + 3) * NM;
    const float* xb = x + (size_t)b * NM;
    float* out = outall + (size_t)b * NM;

    __shared__ float sW[16][65];
    __shared__ float sX[16][65];
    const int t  = threadIdx.x;
    const int n0 = blockIdx.x * 64;
    const int o0 = blockIdx.y * 64;
    const int tx = t & 15, ty = t >> 4;
    const int ln = t & 63, lc = t >> 6;
    const int wj = t & 15, wi = t >> 4;

    float acc[4][4] = {};
    for (int c0 = 0; c0 < CC; c0 += 16) {
#pragma unroll
        for (int r = 0; r < 4; ++r) {
            int i = wi + 16 * r;
            sW[wj][i] = Wo[(o0 + i) * CC + c0 + wj];
        }
#pragma unroll
        for (int r = 0; r < 4; ++r) {
            int cc2 = lc * 4 + r;
            sX[cc2][ln] = (float)O[(size_t)(c0 + cc2) * NN + n0 + ln];
        }
        __syncthreads();
#pragma unroll
        for (int kk = 0; kk < 16; ++kk) {
            float a[4], bb[4];
#pragma unroll
            for (int i = 0; i < 4; ++i) a[i] = sW[kk][ty * 4 + i];
#pragma unroll
            for (int j = 0; j < 4; ++j) bb[j] = sX[kk][tx * 4 + j];
#pragma unroll
            for (int i = 0; i < 4; ++i)
#pragma unroll
                for (int j = 0; j < 4; ++j)
                    acc[i][j] = fmaf(a[i], bb[j], acc[i][j]);
        }
        __syncthreads();
    }
    float g = gamma[0];
#pragma unroll
    for (int i = 0; i < 4; ++i) {
        int o = o0 + ty * 4 + i;
        float bv = bo[o];
#pragma unroll
        for (int j = 0; j < 4; ++j) {
            int n = n0 + tx * 4 + j;
            out[(size_t)o * NN + n] = acc[i][j] + bv + g * xb[(size_t)o * NN + n];
        }
    }
}

// ---------------------------------------------------------------------------
__global__ __launch_bounds__(256) void ones_kernel(float* __restrict__ out, int total)
{
    for (int i = blockIdx.x * 256 + threadIdx.x; i < total; i += gridDim.x * 256)
        out[i] = 1.0f;
}

// ---------------------------------------------------------------------------
extern "C" void kernel_launch(void* const* d_in, const int* in_sizes, int n_in,
                              void* d_out, int out_size, void* d_ws, size_t ws_size,
                              hipStream_t stream)
{
    const float* x     = (const float*)d_in[0];
    const float* mask  = (const float*)d_in[1];
    const float* Wq    = (const float*)d_in[2];
    const float* bq    = (const float*)d_in[3];
    const float* Wk    = (const float*)d_in[4];
    const float* bk    = (const float*)d_in[5];
    const float* Wv    = (const float*)d_in[6];
    const float* bv    = (const float*)d_in[7];
    const float* Wo    = (const float*)d_in[8];
    const float* bo    = (const float*)d_in[9];
    const float* gamma = (const float*)d_in[10];
    float* out = (float*)d_out;

    const size_t slot_bytes = 4 * NM * sizeof(f16);   // 8 MiB
    f16* wsh = (f16*)d_ws;
    int nb = (int)(ws_size / slot_bytes);
    if (nb < 1) {
        ones_kernel<<<2048, 256, 0, stream>>>(out, out_size);
        return;
    }
    if (nb > NB) nb = NB;

    for (int b0 = 0; b0 < NB; b0 += nb) {
        int nbc = NB - b0; if (nbc > nb) nbc = nb;
        dim3 gP(NN / 64, CC / 64, nbc);
        dim3 gF(NN / 64, nbc);
        proj_kernel<<<gP, 256, 0, stream>>>(x, mask, Wq, bq, wsh, 0, 0, b0, 1);
        proj_kernel<<<gP, 256, 0, stream>>>(x, mask, Wk, bk, wsh, 1, 1, b0, 1);
        proj_kernel<<<gP, 256, 0, stream>>>(x, mask, Wv, bv, wsh, 1, 2, b0, 0);
        flash_kernel<<<gF, 256, 0, stream>>>(wsh);
        final_kernel<<<gP, 256, 0, stream>>>(wsh, Wo, bo, x, gamma, out, b0);
    }
}

// Round 6
// 1323.486 us; speedup vs baseline: 6.1061x; 1.0047x over previous
//
#include <hip/hip_runtime.h>

#define CC 256
#define NN 4096
#define NB 8
#define NM ((size_t)CC * NN)   // 1M elems per plane

typedef _Float16 f16;
typedef f16 f16x4 __attribute__((ext_vector_type(4)));
typedef f16 f16x8 __attribute__((ext_vector_type(8)));
typedef float f32x4 __attribute__((ext_vector_type(4)));

// ---------------------------------------------------------------------------
// proj: Y[o,n] = sum_c W[o,c] * x[c,n] * m(n) + bias[o]  -> fp16 plane
// transout=0: plane[o][n] (c-major, for V). transout=1: plane[n][o] (for Q,K).
// grid (NN/64, CC/64, nb), block 256.
// ---------------------------------------------------------------------------
__global__ __launch_bounds__(256) void proj_kernel(
    const float* __restrict__ x, const float* __restrict__ mask,
    const float* __restrict__ W, const float* __restrict__ bias,
    f16* __restrict__ wsh, int invmask, int qkv_off, int b0, int transout)
{
    const int slot = blockIdx.z;
    const int b = b0 + slot;
    const float* xb = x + (size_t)b * NM;
    const float* mb = mask + (size_t)b * NN;
    f16* out = wsh + ((size_t)slot * 4 + qkv_off) * NM;

    __shared__ float sW[16][65];   // [c][o]
    __shared__ float sX[16][65];   // [c][n]
    const int t  = threadIdx.x;
    const int n0 = blockIdx.x * 64;
    const int o0 = blockIdx.y * 64;
    const int tx = t & 15, ty = t >> 4;
    const int ln = t & 63, lc = t >> 6;
    const int wj = t & 15, wi = t >> 4;

    float mm   = mb[n0 + ln];
    float mval = invmask ? (1.0f - mm) : mm;

    float acc[4][4] = {};
    for (int c0 = 0; c0 < CC; c0 += 16) {
#pragma unroll
        for (int r = 0; r < 4; ++r) {
            int i = wi + 16 * r;
            sW[wj][i] = W[(o0 + i) * CC + c0 + wj];
        }
#pragma unroll
        for (int r = 0; r < 4; ++r) {
            int cc2 = lc * 4 + r;
            sX[cc2][ln] = xb[(size_t)(c0 + cc2) * NN + n0 + ln] * mval;
        }
        __syncthreads();
#pragma unroll
        for (int kk = 0; kk < 16; ++kk) {
            float a[4], bb[4];
#pragma unroll
            for (int i = 0; i < 4; ++i) a[i] = sW[kk][ty * 4 + i];
#pragma unroll
            for (int j = 0; j < 4; ++j) bb[j] = sX[kk][tx * 4 + j];
#pragma unroll
            for (int i = 0; i < 4; ++i)
#pragma unroll
                for (int j = 0; j < 4; ++j)
                    acc[i][j] = fmaf(a[i], bb[j], acc[i][j]);
        }
        __syncthreads();
    }
    float bvv[4];
#pragma unroll
    for (int i = 0; i < 4; ++i) bvv[i] = bias[o0 + ty * 4 + i];

    if (transout) {
#pragma unroll
        for (int j = 0; j < 4; ++j) {
            f16x4 pk;
#pragma unroll
            for (int i = 0; i < 4; ++i) pk[i] = (f16)(acc[i][j] + bvv[i]);
            *(f16x4*)(out + (size_t)(n0 + tx * 4 + j) * CC + o0 + ty * 4) = pk;
        }
    } else {
#pragma unroll
        for (int i = 0; i < 4; ++i) {
            f16x4 pk;
#pragma unroll
            for (int j = 0; j < 4; ++j) pk[j] = (f16)(acc[i][j] + bvv[i]);
            *(f16x4*)(out + (size_t)(o0 + ty * 4 + i) * NN + n0 + tx * 4) = pk;
        }
    }
}

// ---------------------------------------------------------------------------
// MFMA flash attention, software-pipelined loads.
// grid (NN/64, nb), block 256 (4 waves). Wave w owns 16 query rows.
// Layouts: q[N][C], k[M][C], v[C][N], o[C][N], all fp16.
// ---------------------------------------------------------------------------
__global__ __launch_bounds__(256, 2) void flash_kernel(f16* __restrict__ wsh)
{
    __shared__ f16 pbuf[4][16 * 88];   // per-wave P tile, pitch 88

    const int t    = threadIdx.x;
    const int w    = t >> 6;
    const int lane = t & 63;
    const int l16  = lane & 15;
    const int quad = lane >> 4;
    const int n0   = blockIdx.x * 64;

    f16* base = wsh + (size_t)blockIdx.y * 4 * NM;
    const f16* qt = base;            // [N][C]
    const f16* kt = base + NM;       // [M][C]
    const f16* vp = base + 2 * NM;   // [C][N]
    f16* op       = base + 3 * NM;   // [C][N]

    // Q fragments resident for the whole m-loop
    const int nrow = n0 + w * 16 + l16;
    f16x8 qf[8];
#pragma unroll
    for (int kc = 0; kc < 8; ++kc)
        qf[kc] = *(const f16x8*)(qt + (size_t)nrow * CC + kc * 32 + quad * 8);

    f32x4 oacc[16];
#pragma unroll
    for (int i = 0; i < 16; ++i) oacc[i] = (f32x4){0.f, 0.f, 0.f, 0.f};
    float M[4] = {-3.0e38f, -3.0e38f, -3.0e38f, -3.0e38f};
    float L[4] = {0.f, 0.f, 0.f, 0.f};

    f16* pw = &pbuf[w][0];

    f16x8 kbuf[2][8];   // ping-pong K fragments (one ms-group each)
    f16x8 vbuf[3][8];   // ring of V chunks (4 cs each)

    // preload K for (m0=0, ms=0)
    {
        const f16* kb = kt + (size_t)l16 * CC + quad * 8;
#pragma unroll
        for (int kc = 0; kc < 8; ++kc)
            kbuf[0][kc] = *(const f16x8*)(kb + kc * 32);
    }

    for (int m0 = 0; m0 < NN; m0 += 64) {
        // ---- S = Q K^T : 16n x 64m, K-dim 256, K-loads pipelined ----
        f32x4 s[4];
#pragma unroll
        for (int ms = 0; ms < 4; ++ms) {
            if (ms < 3) {   // prefetch next ms-group into the other buffer
                const f16* kb = kt + (size_t)(m0 + (ms + 1) * 16 + l16) * CC + quad * 8;
#pragma unroll
                for (int kc = 0; kc < 8; ++kc)
                    kbuf[(ms + 1) & 1][kc] = *(const f16x8*)(kb + kc * 32);
            } else {        // prefetch V chunks 0,1 (independent of softmax)
#pragma unroll
                for (int ch = 0; ch < 2; ++ch)
#pragma unroll
                    for (int i = 0; i < 4; ++i) {
                        const f16* vb = vp + (size_t)((ch * 4 + i) * 16 + l16) * NN + m0 + quad * 8;
                        vbuf[ch][2 * i]     = *(const f16x8*)(vb);
                        vbuf[ch][2 * i + 1] = *(const f16x8*)(vb + 32);
                    }
            }
            f32x4 acc = {0.f, 0.f, 0.f, 0.f};
#pragma unroll
            for (int kc = 0; kc < 8; ++kc)
                acc = __builtin_amdgcn_mfma_f32_16x16x32_f16(qf[kc], kbuf[ms & 1][kc], acc, 0, 0, 0);
            s[ms] = acc;
        }
        // ---- online softmax (rows quad*4+r, private to 16-lane group) ----
        float Mnew[4], alpha[4];
#pragma unroll
        for (int r = 0; r < 4; ++r) {
            float tm = fmaxf(fmaxf(s[0][r], s[1][r]), fmaxf(s[2][r], s[3][r]));
            tm = fmaxf(tm, __shfl_xor(tm, 1, 64));
            tm = fmaxf(tm, __shfl_xor(tm, 2, 64));
            tm = fmaxf(tm, __shfl_xor(tm, 4, 64));
            tm = fmaxf(tm, __shfl_xor(tm, 8, 64));
            Mnew[r]  = fmaxf(M[r], tm);
            alpha[r] = __expf(M[r] - Mnew[r]);
            float p0 = __expf(s[0][r] - Mnew[r]);
            float p1 = __expf(s[1][r] - Mnew[r]);
            float p2 = __expf(s[2][r] - Mnew[r]);
            float p3 = __expf(s[3][r] - Mnew[r]);
            s[0][r] = p0; s[1][r] = p1; s[2][r] = p2; s[3][r] = p3;
            float rs = (p0 + p1) + (p2 + p3);
            rs += __shfl_xor(rs, 1, 64);
            rs += __shfl_xor(rs, 2, 64);
            rs += __shfl_xor(rs, 4, 64);
            rs += __shfl_xor(rs, 8, 64);
            L[r] = L[r] * alpha[r] + rs;
            M[r] = Mnew[r];
        }
        // ---- P -> LDS (fp16), D-layout write ----
#pragma unroll
        for (int ms = 0; ms < 4; ++ms)
#pragma unroll
            for (int r = 0; r < 4; ++r)
                pw[(quad * 4 + r) * 88 + ms * 16 + l16] = (f16)s[ms][r];
        // ---- rescale O only if the running max moved ----
        bool need = (alpha[0] < 1.f) | (alpha[1] < 1.f) |
                    (alpha[2] < 1.f) | (alpha[3] < 1.f);
        if (need) {
#pragma unroll
            for (int cs = 0; cs < 16; ++cs)
#pragma unroll
                for (int r = 0; r < 4; ++r) oacc[cs][r] *= alpha[r];
        }
        asm volatile("s_waitcnt lgkmcnt(0)" ::: "memory");
        // ---- P as A-fragments ----
        f16x8 pf[2];
#pragma unroll
        for (int kp = 0; kp < 2; ++kp)
            pf[kp] = *(const f16x8*)(pw + l16 * 88 + kp * 32 + quad * 8);
        // ---- O += P V^T, V chunks pipelined 2 ahead ----
#pragma unroll
        for (int ch = 0; ch < 4; ++ch) {
            if (ch < 2) {   // prefetch chunk ch+2 into ring slot
                int dst = (ch == 0) ? 2 : 0;
#pragma unroll
                for (int i = 0; i < 4; ++i) {
                    const f16* vb = vp + (size_t)(((ch + 2) * 4 + i) * 16 + l16) * NN + m0 + quad * 8;
                    vbuf[dst][2 * i]     = *(const f16x8*)(vb);
                    vbuf[dst][2 * i + 1] = *(const f16x8*)(vb + 32);
                }
            } else if (ch == 2) {   // prefetch next iteration's K (ms=0)
                const f16* kb = kt + (size_t)(m0 + 64 + l16) * CC + quad * 8;
#pragma unroll
                for (int kc = 0; kc < 8; ++kc)
                    kbuf[0][kc] = *(const f16x8*)(kb + kc * 32);
            }
            const int srcbuf = (ch == 2) ? 2 : (ch == 3 ? 0 : ch);
#pragma unroll
            for (int i = 0; i < 4; ++i) {
                int cs = ch * 4 + i;
                oacc[cs] = __builtin_amdgcn_mfma_f32_16x16x32_f16(pf[0], vbuf[srcbuf][2 * i],     oacc[cs], 0, 0, 0);
                oacc[cs] = __builtin_amdgcn_mfma_f32_16x16x32_f16(pf[1], vbuf[srcbuf][2 * i + 1], oacc[cs], 0, 0, 0);
            }
        }
    }
    // ---- epilogue: divide by denominator, write o[C][N] fp16 ----
    float inv[4];
#pragma unroll
    for (int r = 0; r < 4; ++r) inv[r] = 1.0f / L[r];
#pragma unroll
    for (int cs = 0; cs < 16; ++cs)
#pragma unroll
        for (int r = 0; r < 4; ++r)
            op[(size_t)(cs * 16 + l16) * NN + n0 + w * 16 + quad * 4 + r] =
                (f16)(oacc[cs][r] * inv[r]);
}

// ---------------------------------------------------------------------------
// final: out[o,n] = sum_c Wo[o,c]*O[c,n] + bo[o] + gamma*x[o,n]   (fp32 out)
// grid (NN/64, CC/64, nb), block 256
// ---------------------------------------------------------------------------
__global__ __launch_bounds__(256) void final_kernel(
    const f16* __restrict__ wsh, const float* __restrict__ Wo,
    const float* __restrict__ bo, const float* __restrict__ x,
    const float* __restrict__ gamma, float* __restrict__ outall, int b0)
{
    const int slot = blockIdx.z;
    const int b = b0 + slot;
    const f16* O = wsh + ((size_t)slot * 4 + 3) * NM;
    const float* xb = x + (size_t)b * NM;
    float* out = outall + (size_t)b * NM;

    __shared__ float sW[16][65];
    __shared__ float sX[16][65];
    const int t  = threadIdx.x;
    const int n0 = blockIdx.x * 64;
    const int o0 = blockIdx.y * 64;
    const int tx = t & 15, ty = t >> 4;
    const int ln = t & 63, lc = t >> 6;
    const int wj = t & 15, wi = t >> 4;

    float acc[4][4] = {};
    for (int c0 = 0; c0 < CC; c0 += 16) {
#pragma unroll
        for (int r = 0; r < 4; ++r) {
            int i = wi + 16 * r;
            sW[wj][i] = Wo[(o0 + i) * CC + c0 + wj];
        }
#pragma unroll
        for (int r = 0; r < 4; ++r) {
            int cc2 = lc * 4 + r;
            sX[cc2][ln] = (float)O[(size_t)(c0 + cc2) * NN + n0 + ln];
        }
        __syncthreads();
#pragma unroll
        for (int kk = 0; kk < 16; ++kk) {
            float a[4], bb[4];
#pragma unroll
            for (int i = 0; i < 4; ++i) a[i] = sW[kk][ty * 4 + i];
#pragma unroll
            for (int j = 0; j < 4; ++j) bb[j] = sX[kk][tx * 4 + j];
#pragma unroll
            for (int i = 0; i < 4; ++i)
#pragma unroll
                for (int j = 0; j < 4; ++j)
                    acc[i][j] = fmaf(a[i], bb[j], acc[i][j]);
        }
        __syncthreads();
    }
    float g = gamma[0];
#pragma unroll
    for (int i = 0; i < 4; ++i) {
        int o = o0 + ty * 4 + i;
        float bv = bo[o];
#pragma unroll
        for (int j = 0; j < 4; ++j) {
            int n = n0 + tx * 4 + j;
            out[(size_t)o * NN + n] = acc[i][j] + bv + g * xb[(size_t)o * NN + n];
        }
    }
}

// ---------------------------------------------------------------------------
__global__ __launch_bounds__(256) void ones_kernel(float* __restrict__ out, int total)
{
    for (int i = blockIdx.x * 256 + threadIdx.x; i < total; i += gridDim.x * 256)
        out[i] = 1.0f;
}

// ---------------------------------------------------------------------------
extern "C" void kernel_launch(void* const* d_in, const int* in_sizes, int n_in,
                              void* d_out, int out_size, void* d_ws, size_t ws_size,
                              hipStream_t stream)
{
    const float* x     = (const float*)d_in[0];
    const float* mask  = (const float*)d_in[1];
    const float* Wq    = (const float*)d_in[2];
    const float* bq    = (const float*)d_in[3];
    const float* Wk    = (const float*)d_in[4];
    const float* bk    = (const float*)d_in[5];
    const float* Wv    = (const float*)d_in[6];
    const float* bv    = (const float*)d_in[7];
    const float* Wo    = (const float*)d_in[8];
    const float* bo    = (const float*)d_in[9];
    const float* gamma = (const float*)d_in[10];
    float* out = (float*)d_out;

    const size_t slot_bytes = 4 * NM * sizeof(f16);   // 8 MiB
    f16* wsh = (f16*)d_ws;
    int nb = (int)(ws_size / slot_bytes);
    if (nb < 1) {
        ones_kernel<<<2048, 256, 0, stream>>>(out, out_size);
        return;
    }
    if (nb > NB) nb = NB;

    for (int b0 = 0; b0 < NB; b0 += nb) {
        int nbc = NB - b0; if (nbc > nb) nbc = nb;
        dim3 gP(NN / 64, CC / 64, nbc);
        dim3 gF(NN / 64, nbc);
        proj_kernel<<<gP, 256, 0, stream>>>(x, mask, Wq, bq, wsh, 0, 0, b0, 1);
        proj_kernel<<<gP, 256, 0, stream>>>(x, mask, Wk, bk, wsh, 1, 1, b0, 1);
        proj_kernel<<<gP, 256, 0, stream>>>(x, mask, Wv, bv, wsh, 1, 2, b0, 0);
        flash_kernel<<<gF, 256, 0, stream>>>(wsh);
        final_kernel<<<gP, 256, 0, stream>>>(wsh, Wo, bo, x, gamma, out, b0);
    }
}

// Round 7
// 691.204 us; speedup vs baseline: 11.6917x; 1.9148x over previous
//
#include <hip/hip_runtime.h>

#define CC 256
#define NN 4096
#define NB 8
#define NM ((size_t)CC * NN)   // 1M elems per plane

typedef _Float16 f16;
typedef f16 f16x4 __attribute__((ext_vector_type(4)));
typedef f16 f16x8 __attribute__((ext_vector_type(8)));
typedef float f32x4 __attribute__((ext_vector_type(4)));

// ---------------------------------------------------------------------------
// proj: Y[o,n] = sum_c W[o,c] * x[c,n] * m(n) + bias[o]  -> fp16 plane
// transout=0: plane[o][n] (c-major, for V). transout=1: plane[n][o] (for Q,K).
// grid (NN/64, CC/64, nb), block 256.
// ---------------------------------------------------------------------------
__global__ __launch_bounds__(256) void proj_kernel(
    const float* __restrict__ x, const float* __restrict__ mask,
    const float* __restrict__ W, const float* __restrict__ bias,
    f16* __restrict__ wsh, int invmask, int qkv_off, int b0, int transout)
{
    const int slot = blockIdx.z;
    const int b = b0 + slot;
    const float* xb = x + (size_t)b * NM;
    const float* mb = mask + (size_t)b * NN;
    f16* out = wsh + ((size_t)slot * 4 + qkv_off) * NM;

    __shared__ float sW[16][65];   // [c][o]
    __shared__ float sX[16][65];   // [c][n]
    const int t  = threadIdx.x;
    const int n0 = blockIdx.x * 64;
    const int o0 = blockIdx.y * 64;
    const int tx = t & 15, ty = t >> 4;
    const int ln = t & 63, lc = t >> 6;
    const int wj = t & 15, wi = t >> 4;

    float mm   = mb[n0 + ln];
    float mval = invmask ? (1.0f - mm) : mm;

    float acc[4][4] = {};
    for (int c0 = 0; c0 < CC; c0 += 16) {
#pragma unroll
        for (int r = 0; r < 4; ++r) {
            int i = wi + 16 * r;
            sW[wj][i] = W[(o0 + i) * CC + c0 + wj];
        }
#pragma unroll
        for (int r = 0; r < 4; ++r) {
            int cc2 = lc * 4 + r;
            sX[cc2][ln] = xb[(size_t)(c0 + cc2) * NN + n0 + ln] * mval;
        }
        __syncthreads();
#pragma unroll
        for (int kk = 0; kk < 16; ++kk) {
            float a[4], bb[4];
#pragma unroll
            for (int i = 0; i < 4; ++i) a[i] = sW[kk][ty * 4 + i];
#pragma unroll
            for (int j = 0; j < 4; ++j) bb[j] = sX[kk][tx * 4 + j];
#pragma unroll
            for (int i = 0; i < 4; ++i)
#pragma unroll
                for (int j = 0; j < 4; ++j)
                    acc[i][j] = fmaf(a[i], bb[j], acc[i][j]);
        }
        __syncthreads();
    }
    float bvv[4];
#pragma unroll
    for (int i = 0; i < 4; ++i) bvv[i] = bias[o0 + ty * 4 + i];

    if (transout) {
#pragma unroll
        for (int j = 0; j < 4; ++j) {
            f16x4 pk;
#pragma unroll
            for (int i = 0; i < 4; ++i) pk[i] = (f16)(acc[i][j] + bvv[i]);
            *(f16x4*)(out + (size_t)(n0 + tx * 4 + j) * CC + o0 + ty * 4) = pk;
        }
    } else {
#pragma unroll
        for (int i = 0; i < 4; ++i) {
            f16x4 pk;
#pragma unroll
            for (int j = 0; j < 4; ++j) pk[j] = (f16)(acc[i][j] + bvv[i]);
            *(f16x4*)(out + (size_t)(o0 + ty * 4 + i) * NN + n0 + tx * 4) = pk;
        }
    }
}

// ---------------------------------------------------------------------------
// MFMA flash attention, block-cooperative LDS staging of K/V tiles.
// grid (NN/64, nb), block 256 (4 waves). Wave w owns 16 query rows.
// Layouts: q[N][C], k[M][C], v[C][N], o[C][N], all fp16.
// LDS K/V tiles are stored FRAGMENT-MAJOR: chunk id -> 16B per lane so every
// ds_read_b128 fragment fetch is a contiguous 1KB (bank-conflict-free).
//   K chunk c = ((ms*8+kc)*4+quad)*16 + l16   <-> K[m0+ms*16+l16][kc*32+quad*8..+7]
//   V chunk c = ((cs*2+h )*4+quad)*16 + l16   <-> V[cs*16+l16][m0+h*32+quad*8..+7]
// ---------------------------------------------------------------------------
__global__ __launch_bounds__(256, 2) void flash_kernel(f16* __restrict__ wsh)
{
    __shared__ f16x8 klds[2048];       // 32 KB
    __shared__ f16x8 vlds[2048];       // 32 KB
    __shared__ f16 pbuf[4][16 * 88];   // 11 KB, per-wave P tile

    const int t    = threadIdx.x;
    const int w    = t >> 6;
    const int lane = t & 63;
    const int l16  = lane & 15;
    const int quad = lane >> 4;
    const int n0   = blockIdx.x * 64;

    f16* base = wsh + (size_t)blockIdx.y * 4 * NM;
    const f16* qt = base;            // [N][C]
    const f16* kt = base + NM;       // [M][C]
    const f16* vp = base + 2 * NM;   // [C][N]
    f16* op       = base + 3 * NM;   // [C][N]

    // per-thread staging source offsets (chunk id = i*256 + t)
    int koff[8], voff[8];
#pragma unroll
    for (int i = 0; i < 8; ++i) {
        koff[i] = ((i >> 1) * 16 + (t & 15)) * CC
                + ((i & 1) * 4 + (t >> 6)) * 32 + ((t >> 4) & 3) * 8;
        voff[i] = ((i * 2 + (t >> 7)) * 16 + (t & 15)) * NN
                + ((t >> 6) & 1) * 32 + ((t >> 4) & 3) * 8;
    }

    // Q fragments resident for the whole m-loop
    const int nrow = n0 + w * 16 + l16;
    f16x8 qf[8];
#pragma unroll
    for (int kc = 0; kc < 8; ++kc)
        qf[kc] = *(const f16x8*)(qt + (size_t)nrow * CC + kc * 32 + quad * 8);

    f32x4 oacc[16];
#pragma unroll
    for (int i = 0; i < 16; ++i) oacc[i] = (f32x4){0.f, 0.f, 0.f, 0.f};
    float M[4] = {-3.0e38f, -3.0e38f, -3.0e38f, -3.0e38f};
    float L[4] = {0.f, 0.f, 0.f, 0.f};

    f16* pw = &pbuf[w][0];

    // prologue: fetch tile 0 into registers
    f16x8 kreg[8], vreg[8];
#pragma unroll
    for (int i = 0; i < 8; ++i) {
        kreg[i] = *(const f16x8*)(kt + koff[i]);
        vreg[i] = *(const f16x8*)(vp + voff[i]);
    }

    for (int m0 = 0; m0 < NN; m0 += 64) {
        // ---- publish staged tile to LDS ----
#pragma unroll
        for (int i = 0; i < 8; ++i) {
            klds[i * 256 + t] = kreg[i];
            vlds[i * 256 + t] = vreg[i];
        }
        __syncthreads();
        // ---- issue next tile's global loads (hidden under compute) ----
        if (m0 + 64 < NN) {
#pragma unroll
            for (int i = 0; i < 8; ++i) {
                kreg[i] = *(const f16x8*)(kt + (size_t)(m0 + 64) * CC + koff[i]);
                vreg[i] = *(const f16x8*)(vp + (m0 + 64) + voff[i]);
            }
        }
        // ---- S = Q K^T : 16n x 64m, K-dim 256 ----
        f32x4 s[4];
#pragma unroll
        for (int ms = 0; ms < 4; ++ms) {
            f32x4 acc = {0.f, 0.f, 0.f, 0.f};
#pragma unroll
            for (int kc = 0; kc < 8; ++kc) {
                f16x8 kf = klds[(ms * 8 + kc) * 64 + lane];
                acc = __builtin_amdgcn_mfma_f32_16x16x32_f16(qf[kc], kf, acc, 0, 0, 0);
            }
            s[ms] = acc;
        }
        // ---- online softmax (rows quad*4+r, reduce over l16 lanes) ----
        float Mnew[4], alpha[4];
#pragma unroll
        for (int r = 0; r < 4; ++r) {
            float tm = fmaxf(fmaxf(s[0][r], s[1][r]), fmaxf(s[2][r], s[3][r]));
            tm = fmaxf(tm, __shfl_xor(tm, 1, 64));
            tm = fmaxf(tm, __shfl_xor(tm, 2, 64));
            tm = fmaxf(tm, __shfl_xor(tm, 4, 64));
            tm = fmaxf(tm, __shfl_xor(tm, 8, 64));
            Mnew[r]  = fmaxf(M[r], tm);
            alpha[r] = __expf(M[r] - Mnew[r]);
            float p0 = __expf(s[0][r] - Mnew[r]);
            float p1 = __expf(s[1][r] - Mnew[r]);
            float p2 = __expf(s[2][r] - Mnew[r]);
            float p3 = __expf(s[3][r] - Mnew[r]);
            s[0][r] = p0; s[1][r] = p1; s[2][r] = p2; s[3][r] = p3;
            float rs = (p0 + p1) + (p2 + p3);
            rs += __shfl_xor(rs, 1, 64);
            rs += __shfl_xor(rs, 2, 64);
            rs += __shfl_xor(rs, 4, 64);
            rs += __shfl_xor(rs, 8, 64);
            L[r] = L[r] * alpha[r] + rs;
            M[r] = Mnew[r];
        }
        // ---- P -> per-wave LDS (fp16), D-layout write ----
#pragma unroll
        for (int ms = 0; ms < 4; ++ms)
#pragma unroll
            for (int r = 0; r < 4; ++r)
                pw[(quad * 4 + r) * 88 + ms * 16 + l16] = (f16)s[ms][r];
        // ---- rescale O only if the running max moved ----
        bool need = (alpha[0] < 1.f) | (alpha[1] < 1.f) |
                    (alpha[2] < 1.f) | (alpha[3] < 1.f);
        if (need) {
#pragma unroll
            for (int cs = 0; cs < 16; ++cs)
#pragma unroll
                for (int r = 0; r < 4; ++r) oacc[cs][r] *= alpha[r];
        }
        asm volatile("s_waitcnt lgkmcnt(0)" ::: "memory");
        // ---- P as A-fragments ----
        f16x8 pf[2];
#pragma unroll
        for (int kp = 0; kp < 2; ++kp)
            pf[kp] = *(const f16x8*)(pw + l16 * 88 + kp * 32 + quad * 8);
        // ---- O += P V^T : 16n x 256c ----
#pragma unroll
        for (int cs = 0; cs < 16; ++cs) {
            f16x8 vf0 = vlds[(cs * 2 + 0) * 64 + lane];
            f16x8 vf1 = vlds[(cs * 2 + 1) * 64 + lane];
            oacc[cs] = __builtin_amdgcn_mfma_f32_16x16x32_f16(pf[0], vf0, oacc[cs], 0, 0, 0);
            oacc[cs] = __builtin_amdgcn_mfma_f32_16x16x32_f16(pf[1], vf1, oacc[cs], 0, 0, 0);
        }
        __syncthreads();   // all LDS reads done before next publish
    }
    // ---- epilogue: divide by denominator, write o[C][N] fp16 ----
    float inv[4];
#pragma unroll
    for (int r = 0; r < 4; ++r) inv[r] = 1.0f / L[r];
#pragma unroll
    for (int cs = 0; cs < 16; ++cs)
#pragma unroll
        for (int r = 0; r < 4; ++r)
            op[(size_t)(cs * 16 + l16) * NN + n0 + w * 16 + quad * 4 + r] =
                (f16)(oacc[cs][r] * inv[r]);
}

// ---------------------------------------------------------------------------
// final: out[o,n] = sum_c Wo[o,c]*O[c,n] + bo[o] + gamma*x[o,n]   (fp32 out)
// grid (NN/64, CC/64, nb), block 256
// ---------------------------------------------------------------------------
__global__ __launch_bounds__(256) void final_kernel(
    const f16* __restrict__ wsh, const float* __restrict__ Wo,
    const float* __restrict__ bo, const float* __restrict__ x,
    const float* __restrict__ gamma, float* __restrict__ outall, int b0)
{
    const int slot = blockIdx.z;
    const int b = b0 + slot;
    const f16* O = wsh + ((size_t)slot * 4 + 3) * NM;
    const float* xb = x + (size_t)b * NM;
    float* out = outall + (size_t)b * NM;

    __shared__ float sW[16][65];
    __shared__ float sX[16][65];
    const int t  = threadIdx.x;
    const int n0 = blockIdx.x * 64;
    const int o0 = blockIdx.y * 64;
    const int tx = t & 15, ty = t >> 4;
    const int ln = t & 63, lc = t >> 6;
    const int wj = t & 15, wi = t >> 4;

    float acc[4][4] = {};
    for (int c0 = 0; c0 < CC; c0 += 16) {
#pragma unroll
        for (int r = 0; r < 4; ++r) {
            int i = wi + 16 * r;
            sW[wj][i] = Wo[(o0 + i) * CC + c0 + wj];
        }
#pragma unroll
        for (int r = 0; r < 4; ++r) {
            int cc2 = lc * 4 + r;
            sX[cc2][ln] = (float)O[(size_t)(c0 + cc2) * NN + n0 + ln];
        }
        __syncthreads();
#pragma unroll
        for (int kk = 0; kk < 16; ++kk) {
            float a[4], bb[4];
#pragma unroll
            for (int i = 0; i < 4; ++i) a[i] = sW[kk][ty * 4 + i];
#pragma unroll
            for (int j = 0; j < 4; ++j) bb[j] = sX[kk][tx * 4 + j];
#pragma unroll
            for (int i = 0; i < 4; ++i)
#pragma unroll
                for (int j = 0; j < 4; ++j)
                    acc[i][j] = fmaf(a[i], bb[j], acc[i][j]);
        }
        __syncthreads();
    }
    float g = gamma[0];
#pragma unroll
    for (int i = 0; i < 4; ++i) {
        int o = o0 + ty * 4 + i;
        float bv = bo[o];
#pragma unroll
        for (int j = 0; j < 4; ++j) {
            int n = n0 + tx * 4 + j;
            out[(size_t)o * NN + n] = acc[i][j] + bv + g * xb[(size_t)o * NN + n];
        }
    }
}

// ---------------------------------------------------------------------------
__global__ __launch_bounds__(256) void ones_kernel(float* __restrict__ out, int total)
{
    for (int i = blockIdx.x * 256 + threadIdx.x; i < total; i += gridDim.x * 256)
        out[i] = 1.0f;
}

// ---------------------------------------------------------------------------
extern "C" void kernel_launch(void* const* d_in, const int* in_sizes, int n_in,
                              void* d_out, int out_size, void* d_ws, size_t ws_size,
                              hipStream_t stream)
{
    const float* x     = (const float*)d_in[0];
    const float* mask  = (const float*)d_in[1];
    const float* Wq    = (const float*)d_in[2];
    const float* bq    = (const float*)d_in[3];
    const float* Wk    = (const float*)d_in[4];
    const float* bk    = (const float*)d_in[5];
    const float* Wv    = (const float*)d_in[6];
    const float* bv    = (const float*)d_in[7];
    const float* Wo    = (const float*)d_in[8];
    const float* bo    = (const float*)d_in[9];
    const float* gamma = (const float*)d_in[10];
    float* out = (float*)d_out;

    const size_t slot_bytes = 4 * NM * sizeof(f16);   // 8 MiB
    f16* wsh = (f16*)d_ws;
    int nb = (int)(ws_size / slot_bytes);
    if (nb < 1) {
        ones_kernel<<<2048, 256, 0, stream>>>(out, out_size);
        return;
    }
    if (nb > NB) nb = NB;

    for (int b0 = 0; b0 < NB; b0 += nb) {
        int nbc = NB - b0; if (nbc > nb) nbc = nb;
        dim3 gP(NN / 64, CC / 64, nbc);
        dim3 gF(NN / 64, nbc);
        proj_kernel<<<gP, 256, 0, stream>>>(x, mask, Wq, bq, wsh, 0, 0, b0, 1);
        proj_kernel<<<gP, 256, 0, stream>>>(x, mask, Wk, bk, wsh, 1, 1, b0, 1);
        proj_kernel<<<gP, 256, 0, stream>>>(x, mask, Wv, bv, wsh, 1, 2, b0, 0);
        flash_kernel<<<gF, 256, 0, stream>>>(wsh);
        final_kernel<<<gP, 256, 0, stream>>>(wsh, Wo, bo, x, gamma, out, b0);
    }
}

// Round 8
// 441.674 us; speedup vs baseline: 18.2971x; 1.5650x over previous
//
#include <hip/hip_runtime.h>

#define CC 256
#define NN 4096
#define NB 8
#define NM ((size_t)CC * NN)   // 1M elems per plane

typedef _Float16 f16;
typedef f16 f16x4 __attribute__((ext_vector_type(4)));
typedef f16 f16x8 __attribute__((ext_vector_type(8)));
typedef float f32x4 __attribute__((ext_vector_type(4)));

// ---------------------------------------------------------------------------
// proj_fused: q = Wq(x*m)+bq, k = Wk(x*(1-m))+bk, v = Wv(x*(1-m))+bv, one pass.
// grid (NN/64, nb), block 256 (4 waves). Block covers one 64-n tile, all 256 o
// of all three projections (48 o-chunk jobs; 12 per wave as 6 B-sharing pairs).
// x tiles staged fp16 fragment-major:  unit (kc*4+nc)*64 + lane  holds
// xm[c=kc*32+quad*8 .. +8][n=n0+nc*16+l16]  -> ds_read_b128 conflict-free.
// Outputs: q[N][C], k[M][C] (transposed), v[C][N], matching flash layouts.
// ---------------------------------------------------------------------------
__global__ __launch_bounds__(256, 2) void proj_fused_kernel(
    const float* __restrict__ x, const float* __restrict__ mask,
    const float* __restrict__ Wq, const float* __restrict__ bq,
    const float* __restrict__ Wk, const float* __restrict__ bk,
    const float* __restrict__ Wv, const float* __restrict__ bv,
    f16* __restrict__ wsh, int b0)
{
    __shared__ f16x8 xf[2048];   // 32 KB, (x*m) fragment-major
    __shared__ f16x8 xb[2048];   // 32 KB, (x*(1-m))

    const int t = threadIdx.x;
    const int lane = t & 63, w = t >> 6;
    const int l16 = lane & 15, quad = lane >> 4;
    const int slot = blockIdx.y;
    const int b = b0 + slot;
    const int n0 = blockIdx.x * 64;
    const float* xp = x + (size_t)b * NM;
    f16* base = wsh + (size_t)slot * 4 * NM;

    // ---- stage both masked tiles (x read once, coalesced) ----
    float mf  = mask[(size_t)b * NN + n0 + lane];
    float mbk = 1.0f - mf;
#pragma unroll
    for (int i = 0; i < 8; ++i) {
        int cb = w * 8 + i;                      // 8-channel group
        const float* col = xp + (size_t)cb * 8 * NN + n0 + lane;
        f16x8 vf, vb;
#pragma unroll
        for (int u = 0; u < 8; ++u) {
            float xv = col[(size_t)u * NN];
            vf[u] = (f16)(xv * mf);
            vb[u] = (f16)(xv * mbk);
        }
        int unit = ((cb >> 2) * 4 + (lane >> 4)) * 64 + (cb & 3) * 16 + (lane & 15);
        xf[unit] = vf;
        xb[unit] = vb;
    }
    __syncthreads();

    // ---- 12 jobs per wave = 6 pairs sharing B-fragment reads ----
#pragma unroll
    for (int pr = 0; pr < 6; ++pr) {
        int j0  = w * 12 + pr * 2;               // even, never straddles proj bdry
        int p   = j0 >> 4;                       // 0=q, 1=k, 2=v
        int oc0 = j0 & 15;
        const float* W    = (p == 0) ? Wq : (p == 1) ? Wk : Wv;
        const float* bias = (p == 0) ? bq : (p == 1) ? bk : bv;
        const f16x8* bt   = (p == 0) ? xf : xb;

        f16x8 wf[2][8];
#pragma unroll
        for (int h = 0; h < 2; ++h) {
            const float* wrow = W + (size_t)((oc0 + h) * 16 + l16) * CC + quad * 8;
#pragma unroll
            for (int kc = 0; kc < 8; ++kc) {
                float4 a = *(const float4*)(wrow + kc * 32);
                float4 c = *(const float4*)(wrow + kc * 32 + 4);
                f16x8 f;
                f[0] = (f16)a.x; f[1] = (f16)a.y; f[2] = (f16)a.z; f[3] = (f16)a.w;
                f[4] = (f16)c.x; f[5] = (f16)c.y; f[6] = (f16)c.z; f[7] = (f16)c.w;
                wf[h][kc] = f;
            }
        }
        f32x4 acc[2][4];
#pragma unroll
        for (int h = 0; h < 2; ++h)
#pragma unroll
            for (int nc = 0; nc < 4; ++nc) acc[h][nc] = (f32x4){0.f, 0.f, 0.f, 0.f};
#pragma unroll
        for (int nc = 0; nc < 4; ++nc)
#pragma unroll
            for (int kc = 0; kc < 8; ++kc) {
                f16x8 bf = bt[(kc * 4 + nc) * 64 + lane];
                acc[0][nc] = __builtin_amdgcn_mfma_f32_16x16x32_f16(wf[0][kc], bf, acc[0][nc], 0, 0, 0);
                acc[1][nc] = __builtin_amdgcn_mfma_f32_16x16x32_f16(wf[1][kc], bf, acc[1][nc], 0, 0, 0);
            }
#pragma unroll
        for (int h = 0; h < 2; ++h) {
            int oc = oc0 + h;
            float bvv[4];
#pragma unroll
            for (int r = 0; r < 4; ++r) bvv[r] = bias[oc * 16 + quad * 4 + r];
            if (p == 2) {                        // v [C][N]
                f16* vpl = base + 2 * NM;
#pragma unroll
                for (int nc = 0; nc < 4; ++nc)
#pragma unroll
                    for (int r = 0; r < 4; ++r)
                        vpl[(size_t)(oc * 16 + quad * 4 + r) * NN + n0 + nc * 16 + l16] =
                            (f16)(acc[h][nc][r] + bvv[r]);
            } else {                             // q/k [N][C]
                f16* qpl = base + (size_t)p * NM;
#pragma unroll
                for (int nc = 0; nc < 4; ++nc) {
                    f16x4 pk;
#pragma unroll
                    for (int r = 0; r < 4; ++r) pk[r] = (f16)(acc[h][nc][r] + bvv[r]);
                    *(f16x4*)(qpl + (size_t)(n0 + nc * 16 + l16) * CC + oc * 16 + quad * 4) = pk;
                }
            }
        }
    }
}

// ---------------------------------------------------------------------------
// MFMA flash attention, block-cooperative LDS staging (unchanged from R7).
// ---------------------------------------------------------------------------
__global__ __launch_bounds__(256, 2) void flash_kernel(f16* __restrict__ wsh)
{
    __shared__ f16x8 klds[2048];       // 32 KB
    __shared__ f16x8 vlds[2048];       // 32 KB
    __shared__ f16 pbuf[4][16 * 88];   // 11 KB, per-wave P tile

    const int t    = threadIdx.x;
    const int w    = t >> 6;
    const int lane = t & 63;
    const int l16  = lane & 15;
    const int quad = lane >> 4;
    const int n0   = blockIdx.x * 64;

    f16* base = wsh + (size_t)blockIdx.y * 4 * NM;
    const f16* qt = base;            // [N][C]
    const f16* kt = base + NM;       // [M][C]
    const f16* vp = base + 2 * NM;   // [C][N]
    f16* op       = base + 3 * NM;   // [C][N]

    int koff[8], voff[8];
#pragma unroll
    for (int i = 0; i < 8; ++i) {
        koff[i] = ((i >> 1) * 16 + (t & 15)) * CC
                + ((i & 1) * 4 + (t >> 6)) * 32 + ((t >> 4) & 3) * 8;
        voff[i] = ((i * 2 + (t >> 7)) * 16 + (t & 15)) * NN
                + ((t >> 6) & 1) * 32 + ((t >> 4) & 3) * 8;
    }

    const int nrow = n0 + w * 16 + l16;
    f16x8 qf[8];
#pragma unroll
    for (int kc = 0; kc < 8; ++kc)
        qf[kc] = *(const f16x8*)(qt + (size_t)nrow * CC + kc * 32 + quad * 8);

    f32x4 oacc[16];
#pragma unroll
    for (int i = 0; i < 16; ++i) oacc[i] = (f32x4){0.f, 0.f, 0.f, 0.f};
    float M[4] = {-3.0e38f, -3.0e38f, -3.0e38f, -3.0e38f};
    float L[4] = {0.f, 0.f, 0.f, 0.f};

    f16* pw = &pbuf[w][0];

    f16x8 kreg[8], vreg[8];
#pragma unroll
    for (int i = 0; i < 8; ++i) {
        kreg[i] = *(const f16x8*)(kt + koff[i]);
        vreg[i] = *(const f16x8*)(vp + voff[i]);
    }

    for (int m0 = 0; m0 < NN; m0 += 64) {
#pragma unroll
        for (int i = 0; i < 8; ++i) {
            klds[i * 256 + t] = kreg[i];
            vlds[i * 256 + t] = vreg[i];
        }
        __syncthreads();
        if (m0 + 64 < NN) {
#pragma unroll
            for (int i = 0; i < 8; ++i) {
                kreg[i] = *(const f16x8*)(kt + (size_t)(m0 + 64) * CC + koff[i]);
                vreg[i] = *(const f16x8*)(vp + (m0 + 64) + voff[i]);
            }
        }
        f32x4 s[4];
#pragma unroll
        for (int ms = 0; ms < 4; ++ms) {
            f32x4 acc = {0.f, 0.f, 0.f, 0.f};
#pragma unroll
            for (int kc = 0; kc < 8; ++kc) {
                f16x8 kf = klds[(ms * 8 + kc) * 64 + lane];
                acc = __builtin_amdgcn_mfma_f32_16x16x32_f16(qf[kc], kf, acc, 0, 0, 0);
            }
            s[ms] = acc;
        }
        float Mnew[4], alpha[4];
#pragma unroll
        for (int r = 0; r < 4; ++r) {
            float tm = fmaxf(fmaxf(s[0][r], s[1][r]), fmaxf(s[2][r], s[3][r]));
            tm = fmaxf(tm, __shfl_xor(tm, 1, 64));
            tm = fmaxf(tm, __shfl_xor(tm, 2, 64));
            tm = fmaxf(tm, __shfl_xor(tm, 4, 64));
            tm = fmaxf(tm, __shfl_xor(tm, 8, 64));
            Mnew[r]  = fmaxf(M[r], tm);
            alpha[r] = __expf(M[r] - Mnew[r]);
            float p0 = __expf(s[0][r] - Mnew[r]);
            float p1 = __expf(s[1][r] - Mnew[r]);
            float p2 = __expf(s[2][r] - Mnew[r]);
            float p3 = __expf(s[3][r] - Mnew[r]);
            s[0][r] = p0; s[1][r] = p1; s[2][r] = p2; s[3][r] = p3;
            float rs = (p0 + p1) + (p2 + p3);
            rs += __shfl_xor(rs, 1, 64);
            rs += __shfl_xor(rs, 2, 64);
            rs += __shfl_xor(rs, 4, 64);
            rs += __shfl_xor(rs, 8, 64);
            L[r] = L[r] * alpha[r] + rs;
            M[r] = Mnew[r];
        }
#pragma unroll
        for (int ms = 0; ms < 4; ++ms)
#pragma unroll
            for (int r = 0; r < 4; ++r)
                pw[(quad * 4 + r) * 88 + ms * 16 + l16] = (f16)s[ms][r];
        bool need = (alpha[0] < 1.f) | (alpha[1] < 1.f) |
                    (alpha[2] < 1.f) | (alpha[3] < 1.f);
        if (need) {
#pragma unroll
            for (int cs = 0; cs < 16; ++cs)
#pragma unroll
                for (int r = 0; r < 4; ++r) oacc[cs][r] *= alpha[r];
        }
        asm volatile("s_waitcnt lgkmcnt(0)" ::: "memory");
        f16x8 pf[2];
#pragma unroll
        for (int kp = 0; kp < 2; ++kp)
            pf[kp] = *(const f16x8*)(pw + l16 * 88 + kp * 32 + quad * 8);
#pragma unroll
        for (int cs = 0; cs < 16; ++cs) {
            f16x8 vf0 = vlds[(cs * 2 + 0) * 64 + lane];
            f16x8 vf1 = vlds[(cs * 2 + 1) * 64 + lane];
            oacc[cs] = __builtin_amdgcn_mfma_f32_16x16x32_f16(pf[0], vf0, oacc[cs], 0, 0, 0);
            oacc[cs] = __builtin_amdgcn_mfma_f32_16x16x32_f16(pf[1], vf1, oacc[cs], 0, 0, 0);
        }
        __syncthreads();
    }
    float inv[4];
#pragma unroll
    for (int r = 0; r < 4; ++r) inv[r] = 1.0f / L[r];
#pragma unroll
    for (int cs = 0; cs < 16; ++cs)
#pragma unroll
        for (int r = 0; r < 4; ++r)
            op[(size_t)(cs * 16 + l16) * NN + n0 + w * 16 + quad * 4 + r] =
                (f16)(oacc[cs][r] * inv[r]);
}

// ---------------------------------------------------------------------------
// final (MFMA): out[o,n] = Wo·O + bo + gamma*x, fp32 out.
// grid (NN/64, nb), block 256. Same frag-major staging as proj_fused.
// ---------------------------------------------------------------------------
__global__ __launch_bounds__(256, 2) void final_kernel(
    const f16* __restrict__ wsh, const float* __restrict__ Wo,
    const float* __restrict__ bo, const float* __restrict__ x,
    const float* __restrict__ gamma, float* __restrict__ outall, int b0)
{
    __shared__ f16x8 ot[2048];   // 32 KB O tile, fragment-major

    const int t = threadIdx.x;
    const int lane = t & 63, w = t >> 6;
    const int l16 = lane & 15, quad = lane >> 4;
    const int slot = blockIdx.y;
    const int b = b0 + slot;
    const int n0 = blockIdx.x * 64;
    const f16* O = wsh + ((size_t)slot * 4 + 3) * NM;
    const float* xp = x + (size_t)b * NM;
    float* outp = outall + (size_t)b * NM;

#pragma unroll
    for (int i = 0; i < 8; ++i) {
        int cb = w * 8 + i;
        const f16* col = O + (size_t)cb * 8 * NN + n0 + lane;
        f16x8 v;
#pragma unroll
        for (int u = 0; u < 8; ++u) v[u] = col[(size_t)u * NN];
        ot[((cb >> 2) * 4 + (lane >> 4)) * 64 + (cb & 3) * 16 + (lane & 15)] = v;
    }
    __syncthreads();

    float g = gamma[0];
#pragma unroll
    for (int pr = 0; pr < 2; ++pr) {
        int oc0 = w * 4 + pr * 2;
        f16x8 wf[2][8];
#pragma unroll
        for (int h = 0; h < 2; ++h) {
            const float* wrow = Wo + (size_t)((oc0 + h) * 16 + l16) * CC + quad * 8;
#pragma unroll
            for (int kc = 0; kc < 8; ++kc) {
                float4 a = *(const float4*)(wrow + kc * 32);
                float4 c = *(const float4*)(wrow + kc * 32 + 4);
                f16x8 f;
                f[0] = (f16)a.x; f[1] = (f16)a.y; f[2] = (f16)a.z; f[3] = (f16)a.w;
                f[4] = (f16)c.x; f[5] = (f16)c.y; f[6] = (f16)c.z; f[7] = (f16)c.w;
                wf[h][kc] = f;
            }
        }
        f32x4 acc[2][4];
#pragma unroll
        for (int h = 0; h < 2; ++h)
#pragma unroll
            for (int nc = 0; nc < 4; ++nc) acc[h][nc] = (f32x4){0.f, 0.f, 0.f, 0.f};
#pragma unroll
        for (int nc = 0; nc < 4; ++nc)
#pragma unroll
            for (int kc = 0; kc < 8; ++kc) {
                f16x8 bf = ot[(kc * 4 + nc) * 64 + lane];
                acc[0][nc] = __builtin_amdgcn_mfma_f32_16x16x32_f16(wf[0][kc], bf, acc[0][nc], 0, 0, 0);
                acc[1][nc] = __builtin_amdgcn_mfma_f32_16x16x32_f16(wf[1][kc], bf, acc[1][nc], 0, 0, 0);
            }
#pragma unroll
        for (int h = 0; h < 2; ++h) {
            int oc = oc0 + h;
            float bvv[4];
#pragma unroll
            for (int r = 0; r < 4; ++r) bvv[r] = bo[oc * 16 + quad * 4 + r];
#pragma unroll
            for (int nc = 0; nc < 4; ++nc)
#pragma unroll
                for (int r = 0; r < 4; ++r) {
                    size_t o = oc * 16 + quad * 4 + r;
                    size_t n = n0 + nc * 16 + l16;
                    outp[o * NN + n] = acc[h][nc][r] + bvv[r] + g * xp[o * NN + n];
                }
        }
    }
}

// ---------------------------------------------------------------------------
__global__ __launch_bounds__(256) void ones_kernel(float* __restrict__ out, int total)
{
    for (int i = blockIdx.x * 256 + threadIdx.x; i < total; i += gridDim.x * 256)
        out[i] = 1.0f;
}

// ---------------------------------------------------------------------------
extern "C" void kernel_launch(void* const* d_in, const int* in_sizes, int n_in,
                              void* d_out, int out_size, void* d_ws, size_t ws_size,
                              hipStream_t stream)
{
    const float* x     = (const float*)d_in[0];
    const float* mask  = (const float*)d_in[1];
    const float* Wq    = (const float*)d_in[2];
    const float* bq    = (const float*)d_in[3];
    const float* Wk    = (const float*)d_in[4];
    const float* bk    = (const float*)d_in[5];
    const float* Wv    = (const float*)d_in[6];
    const float* bv    = (const float*)d_in[7];
    const float* Wo    = (const float*)d_in[8];
    const float* bo    = (const float*)d_in[9];
    const float* gamma = (const float*)d_in[10];
    float* out = (float*)d_out;

    const size_t slot_bytes = 4 * NM * sizeof(f16);   // 8 MiB
    f16* wsh = (f16*)d_ws;
    int nb = (int)(ws_size / slot_bytes);
    if (nb < 1) {
        ones_kernel<<<2048, 256, 0, stream>>>(out, out_size);
        return;
    }
    if (nb > NB) nb = NB;

    for (int b0 = 0; b0 < NB; b0 += nb) {
        int nbc = NB - b0; if (nbc > nb) nbc = nb;
        dim3 gT(NN / 64, nbc);
        proj_fused_kernel<<<gT, 256, 0, stream>>>(x, mask, Wq, bq, Wk, bk, Wv, bv, wsh, b0);
        flash_kernel<<<gT, 256, 0, stream>>>(wsh);
        final_kernel<<<gT, 256, 0, stream>>>(wsh, Wo, bo, x, gamma, out, b0);
    }
}